// Round 15
// baseline (192.066 us; speedup 1.0000x reference)
//
#include <hip/hip_runtime.h>
#include <hip/hip_bf16.h>
#include <math.h>

// Problem constants
#define NTOK 25088      // 8*56*56
#define HW_  3136
#define HH   56
#define WW   56
#define CCH  256
#define NGRP 16
#define NPTS 9
#define HIDN 1024
#define NOFFM 432       // merged off(288)+mask(144) row width
#define TPB  8          // tokens per dcn block (thread = token x 8 channels)

typedef __attribute__((ext_vector_type(8))) __bf16 bf16x8;
typedef __attribute__((ext_vector_type(4))) __bf16 bf16x4;
typedef __attribute__((ext_vector_type(4))) float  f32x4;
typedef __attribute__((ext_vector_type(4))) _Float16 f16x4;
typedef __attribute__((ext_vector_type(8))) _Float16 f16x8;

static __device__ __forceinline__ void gl_lds16(const void* g, void* l) {
    __builtin_amdgcn_global_load_lds((const __attribute__((address_space(1))) void*)g,
                                     (__attribute__((address_space(3))) void*)l, 16, 0, 0);
}

static __device__ __forceinline__ f16x8 splat8(_Float16 w) {
    f16x8 r = {w, w, w, w, w, w, w, w};
    return r;
}

// tanh-form GELU via identity 0.5v(1+tanh z) = v * sigmoid(2z); fast rcp.
static __device__ __forceinline__ float gelu_fast(float v) {
    float v2 = v * v;
    float z2 = fmaf(0.0713548163f * v, v2, 1.5957691216f * v);   // 2z
    float r  = __builtin_amdgcn_rcpf(__expf(-z2) + 1.0f);        // sigmoid(2z)
    return v * r;
}

// ---------------- weight cvt + bias concat + LN1, fused (independent block ranges) ----------------
__global__ __launch_bounds__(256)
void cvtln_kernel(const float* __restrict__ inp_w, const float* __restrict__ out_w,
                  const float* __restrict__ off_w, const float* __restrict__ mask_w,
                  const float* __restrict__ fc1_w, const float* __restrict__ fc2_w,
                  const float* __restrict__ off_b, const float* __restrict__ mask_b,
                  __bf16* wib, __bf16* wob, __bf16* wcat, __bf16* w1b, __bf16* w2b,
                  float* bcat,
                  const float* __restrict__ x, const float* __restrict__ ln1_g,
                  const float* __restrict__ ln1_b, __bf16* __restrict__ lnb) {
    if (blockIdx.x < 750) {
        int i = blockIdx.x * 256 + threadIdx.x;
        if (i >= 191488) {
            int j = i - 191488;
            if (j < 432) bcat[j] = (j < 288) ? off_b[j] : mask_b[j - 288];
            return;
        }
        const float* s; __bf16* d; int off;
        if (i < 16384)       { s = inp_w;  d = wib;          off = i; }
        else if (i < 32768)  { s = out_w;  d = wob;          off = i - 16384; }
        else if (i < 51200)  { s = off_w;  d = wcat;         off = i - 32768; }
        else if (i < 60416)  { s = mask_w; d = wcat + 73728; off = i - 51200; }
        else if (i < 125952) { s = fc1_w;  d = w1b;          off = i - 60416; }
        else                 { s = fc2_w;  d = w2b;          off = i - 125952; }
        float4 v = ((const float4*)s)[off];
        bf16x4 o = {(__bf16)v.x, (__bf16)v.y, (__bf16)v.z, (__bf16)v.w};
        ((bf16x4*)d)[off] = o;
        return;
    }
    // LN1: one wave per token, f32 in, bf16 out
    int gid  = (blockIdx.x - 750) * 256 + threadIdx.x;
    int t    = gid >> 6;
    int lane = threadIdx.x & 63;
    if (t >= NTOK) return;
    float4 v = ((const float4*)(x + (size_t)t * CCH))[lane];
    float s = v.x + v.y + v.z + v.w;
#pragma unroll
    for (int o = 1; o < 64; o <<= 1) s += __shfl_xor(s, o);
    float mu = s * 0.00390625f;
    float dx = v.x - mu, dy = v.y - mu, dz = v.z - mu, dw = v.w - mu;
    float q = dx * dx + dy * dy + dz * dz + dw * dw;
#pragma unroll
    for (int o = 1; o < 64; o <<= 1) q += __shfl_xor(q, o);
    float rstd = rsqrtf(q * 0.00390625f + 1e-6f);
    float4 gg = ((const float4*)ln1_g)[lane];
    float4 bb = ((const float4*)ln1_b)[lane];
    bf16x4 ob = {(__bf16)(dx * rstd * gg.x + bb.x), (__bf16)(dy * rstd * gg.y + bb.y),
                 (__bf16)(dz * rstd * gg.z + bb.z), (__bf16)(dw * rstd * gg.w + bb.w)};
    ((bf16x4*)(lnb + (size_t)t * CCH))[lane] = ob;
}

// ---------------- LayerNorm: bf16 in, bf16 out ----------------
__global__ __launch_bounds__(256)
void ln_b_kernel(const __bf16* __restrict__ x, const float* __restrict__ g,
                 const float* __restrict__ b, __bf16* __restrict__ outb) {
    int gid  = blockIdx.x * 256 + threadIdx.x;
    int t    = gid >> 6;
    int lane = threadIdx.x & 63;
    if (t >= NTOK) return;
    bf16x4 vb = ((const bf16x4*)(x + (size_t)t * CCH))[lane];
    float vx = (float)vb[0], vy = (float)vb[1], vz = (float)vb[2], vw = (float)vb[3];
    float s = vx + vy + vz + vw;
#pragma unroll
    for (int o = 1; o < 64; o <<= 1) s += __shfl_xor(s, o);
    float mu = s * 0.00390625f;
    float dx = vx - mu, dy = vy - mu, dz = vz - mu, dw = vw - mu;
    float q = dx * dx + dy * dy + dz * dz + dw * dw;
#pragma unroll
    for (int o = 1; o < 64; o <<= 1) q += __shfl_xor(q, o);
    float rstd = rsqrtf(q * 0.00390625f + 1e-6f);
    float4 gg = ((const float4*)g)[lane];
    float4 bb = ((const float4*)b)[lane];
    bf16x4 ob = {(__bf16)(dx * rstd * gg.x + bb.x), (__bf16)(dy * rstd * gg.y + bb.y),
                 (__bf16)(dz * rstd * gg.z + bb.z), (__bf16)(dw * rstd * gg.w + bb.w)};
    ((bf16x4*)(outb + (size_t)t * CCH))[lane] = ob;
}

// ---------------- depthwise 3x3 conv (pad 1), bf16 in, thread = token x 4 channels ----------------
__global__ __launch_bounds__(256)
void dwconv_kernel(const __bf16* __restrict__ ln, const float* __restrict__ wt,
                   const float* __restrict__ bias, __bf16* __restrict__ out) {
    int gid = blockIdx.x * 256 + threadIdx.x;
    int t = gid >> 6;
    int cq = gid & 63;
    if (t >= NTOK) return;
    int n = t / HW_, hw = t % HW_;
    int h = hw / WW, w0 = hw % WW;
    float4 a = ((const float4*)bias)[cq];
    const bf16x4* l4 = (const bf16x4*)ln;
    const float4* w4 = (const float4*)wt;
#pragma unroll
    for (int ky = 0; ky < 3; ++ky) {
        int y = h + ky - 1;
        if (y < 0 || y >= HH) continue;
#pragma unroll
        for (int kx = 0; kx < 3; ++kx) {
            int x = w0 + kx - 1;
            if (x < 0 || x >= WW) continue;
            bf16x4 v = l4[(size_t)(n * HW_ + y * WW + x) * 64 + cq];
            float4 ww = w4[(ky * 3 + kx) * 64 + cq];
            a.x += (float)v[0] * ww.x; a.y += (float)v[1] * ww.y;
            a.z += (float)v[2] * ww.z; a.w += (float)v[3] * ww.w;
        }
    }
    bf16x4 ob = {(__bf16)a.x, (__bf16)a.y, (__bf16)a.z, (__bf16)a.w};
    ((bf16x4*)out)[(size_t)t * 64 + cq] = ob;
}

// ---------------- GEMM body: out[M,N] = A[M,K] @ W[N,K]^T + bias ----------------
// BM=64 x BN=256, 256 threads = 4 waves, wave tile 64x64 (acc 4x4). Depth-2 prefetch,
// COUNTED vmcnt(5). A: linear LDS rows, slot XOR s=(row>>2)&3. B: row-permuted LDS
// (row r holds W-row n0+64*(r>>6)+4*(r&15)+((r>>4)&3)), slot XOR s=(r>>1)&3 ->
// lane owns 4 consecutive output cols. NO launch_bounds 2nd arg (r10/r11 spills).
// EPI 3: bf16 = gemm+bias ; EPI 4: bf16 = gemm+bias+resid_f32 ; EPI 6: fp16 = gemm+bias
template <int EPI>
static __device__ __forceinline__ void gemm_body(
        const __bf16* __restrict__ A, const __bf16* __restrict__ W,
        const float* __restrict__ bias, const float* __restrict__ residf,
        float* __restrict__ outf, __bf16* __restrict__ outb,
        const int Ndim, const int Kdim, const int NB, const int lin) {
    __shared__ __align__(16) __bf16 Alds[2][64 * 32];    // 8 KB
    __shared__ __align__(16) __bf16 Blds[2][256 * 32];   // 32 KB

    const int tid  = threadIdx.x;
    const int w    = tid >> 6;
    const int lane = tid & 63;
    const int m0 = (lin / NB) * 64;
    const int n0 = (lin % NB) * 256;
    const int wc = w * 64;

    f32x4 acc[4][4];
#pragma unroll
    for (int i = 0; i < 4; ++i)
#pragma unroll
        for (int j = 0; j < 4; ++j) acc[i][j] = (f32x4){0.f, 0.f, 0.f, 0.f};

    const char* Ab = (const char*)A;
    const char* Wb = (const char*)W;
    char* AL = (char*)&Alds[0][0];
    char* BL = (char*)&Blds[0][0];
    const size_t rb = (size_t)Kdim * 2;

    const char* gsrc[5];
    char*       ldst[5];
    int         lstep[5];
#pragma unroll
    for (int k = 0; k < 5; ++k) {
        const int sg = w * 5 + k;
        if (sg < 4) {          // A segment
            const int p  = sg * 64 + lane;
            const int rw = p >> 2;
            const int ch = (p & 3) ^ ((p >> 4) & 3);
            gsrc[k]  = Ab + (size_t)(m0 + rw) * rb + ch * 16;
            ldst[k]  = AL + sg * 1024;
            lstep[k] = 4096;
        } else {               // B segment
            const int p  = (sg - 4) * 64 + lane;
            const int r  = p >> 2;
            int bR = n0 + ((r >> 6) << 6) + 4 * (r & 15) + ((r >> 4) & 3);
            if (bR > Ndim - 1) bR = Ndim - 1;
            const int ch = (p & 3) ^ ((p >> 3) & 3);
            gsrc[k]  = Wb + (size_t)bR * rb + ch * 16;
            ldst[k]  = BL + (sg - 4) * 1024;
            lstep[k] = 16384;
        }
    }

#define STAGE(BUF, TILE)                                              \
    do {                                                              \
        const size_t kb_ = (size_t)(TILE) * 64;                       \
        _Pragma("unroll")                                             \
        for (int k = 0; k < 5; ++k)                                   \
            gl_lds16(gsrc[k] + kb_, ldst[k] + (BUF) * lstep[k]);      \
    } while (0)

    const int mrow = lane & 15;
    const int q    = lane >> 4;
    const int kA   = ((q ^ (mrow >> 2)) & 3) * 16;
    const int kB   = ((q ^ (mrow >> 1)) & 3) * 16;

    const int nt = Kdim >> 5;
    STAGE(0, 0);
    if (nt > 1) STAGE(1, 1);
    for (int i = 0; i < nt; ++i) {
        const int cur = i & 1;
        if (i + 1 < nt) asm volatile("s_waitcnt vmcnt(5)" ::: "memory");
        else            asm volatile("s_waitcnt vmcnt(0)" ::: "memory");
        __builtin_amdgcn_s_barrier();     // tile i resident in buf[cur] for all waves
        bf16x8 af[4], bfr[4];
#pragma unroll
        for (int ii = 0; ii < 4; ++ii)
            af[ii] = *(const bf16x8*)(AL + cur * 4096 + (ii * 16 + mrow) * 64 + kA);
#pragma unroll
        for (int ii = 0; ii < 4; ++ii)
            bfr[ii] = *(const bf16x8*)(BL + cur * 16384 + (wc + ii * 16 + mrow) * 64 + kB);
#pragma unroll
        for (int mi = 0; mi < 4; ++mi)
#pragma unroll
            for (int ni = 0; ni < 4; ++ni)
                acc[mi][ni] = __builtin_amdgcn_mfma_f32_16x16x32_bf16(af[mi], bfr[ni], acc[mi][ni], 0, 0, 0);
        __builtin_amdgcn_s_barrier();     // all waves consumed buf[cur]; safe to overwrite
        if (i + 2 < nt) STAGE(cur, i + 2);
    }
#undef STAGE

    const int coll = lane & 15;
    const int rowh = q * 4;
    const int col0 = n0 + wc + 4 * coll;
    if (col0 < Ndim) {
        const float4 bv = *(const float4*)(bias + col0);
#pragma unroll
        for (int mi = 0; mi < 4; ++mi) {
#pragma unroll
            for (int j = 0; j < 4; ++j) {
                const int row = m0 + mi * 16 + rowh + j;
                const size_t idx = (size_t)row * (size_t)Ndim + col0;
                float4 v = make_float4(acc[mi][0][j] + bv.x, acc[mi][1][j] + bv.y,
                                       acc[mi][2][j] + bv.z, acc[mi][3][j] + bv.w);
                if (EPI == 3) {
                    bf16x4 ob = {(__bf16)v.x, (__bf16)v.y, (__bf16)v.z, (__bf16)v.w};
                    *(bf16x4*)(outb + idx) = ob;
                } else if (EPI == 4) {
                    const float4 r = *(const float4*)(residf + idx);
                    bf16x4 ob = {(__bf16)(v.x + r.x), (__bf16)(v.y + r.y),
                                 (__bf16)(v.z + r.z), (__bf16)(v.w + r.w)};
                    *(bf16x4*)(outb + idx) = ob;
                } else {   // EPI 6: fp16 out
                    f16x4 ob = {(_Float16)v.x, (_Float16)v.y, (_Float16)v.z, (_Float16)v.w};
                    *(f16x4*)((_Float16*)outb + idx) = ob;
                }
            }
        }
    }
}

template <int EPI>
__global__ __launch_bounds__(256)
void gemm_kernel(const __bf16* __restrict__ A, const __bf16* __restrict__ W,
                 const float* __restrict__ bias, const float* __restrict__ residf,
                 float* __restrict__ outf, __bf16* __restrict__ outb,
                 const int Ndim, const int Kdim, const int NB) {
    const int chunk = gridDim.x >> 3;
    const int lin   = (blockIdx.x & 7) * chunk + (blockIdx.x >> 3);
    gemm_body<EPI>(A, W, bias, residf, outf, outb, Ndim, Kdim, NB, lin);
}

// two independent projections in one dispatch: offm (bf16 out) + inp (fp16 out)
__global__ __launch_bounds__(256)
void gemm_dual_kernel(const __bf16* __restrict__ A1, const __bf16* __restrict__ W1,
                      const float* __restrict__ b1, __bf16* __restrict__ o1,
                      const int N1, const int NB1, const int split,
                      const __bf16* __restrict__ A2, const __bf16* __restrict__ W2,
                      const float* __restrict__ b2, __bf16* __restrict__ o2,
                      const int N2, const int NB2) {
    const int chunk = gridDim.x >> 3;
    const int lin   = (blockIdx.x & 7) * chunk + (blockIdx.x >> 3);
    if (lin < split)
        gemm_body<3>(A1, W1, b1, nullptr, nullptr, o1, N1, 256, NB1, lin);
    else
        gemm_body<6>(A2, W2, b2, nullptr, nullptr, o2, N2, 256, NB2, lin - split);
}

// ---------------- fused MLP: out = (gelu(l2b @ w1^T + b1)) @ w2^T + b2 + yb ----------------
// Block = 64 rows x full widths; 4 hidden chunks of 256. Phase 1 computes h-chunk with
// the standard staging; epilogue writes h (bf16, gelu'd) into Hlds laid out EXACTLY as
// the A-operand tile (row*64B, 16B-slot XOR s=(row>>2)&3) so phase 2's ds_reads reuse
// the kA pattern. Phase 2 accumulates acc2 += h @ w2-chunk^T (B-only staging, vmcnt(4)).
// h1 never touches HBM (saves ~103MB). Numerics identical to split fc1/fc2.
// NO launch_bounds 2nd arg (r10/r11 spill lesson). LDS 72KB -> 2 blocks/CU.
__global__ __launch_bounds__(256)
void mlp_kernel(const __bf16* __restrict__ A, const __bf16* __restrict__ W1,
                const __bf16* __restrict__ W2, const float* __restrict__ b1,
                const float* __restrict__ b2, const __bf16* __restrict__ yb,
                float* __restrict__ out) {
    __shared__ __align__(16) __bf16 Alds[2][64 * 32];    // 8 KB
    __shared__ __align__(16) __bf16 Blds[2][256 * 32];   // 32 KB
    __shared__ __align__(16) __bf16 Hlds[8][64 * 32];    // 32 KB, [kstep][A-tile layout]

    const int tid  = threadIdx.x;
    const int w    = tid >> 6;
    const int lane = tid & 63;
    // XCD-chunked bijective remap: 392 = 8 x 49
    const int lin = (blockIdx.x & 7) * 49 + (blockIdx.x >> 3);
    const int m0  = lin * 64;
    const int wc  = w * 64;

    const char* Ab  = (const char*)A;
    const char* W1b = (const char*)W1;
    const char* W2b = (const char*)W2;
    char* AL = (char*)&Alds[0][0];
    char* BL = (char*)&Blds[0][0];
    char* HL = (char*)&Hlds[0][0];

    // phase-1 staging segs: A (l2b, rb=512B) segs 0-3, B (w1 chunk rows, rb=512B) segs 4-19
    const char* g1[5]; char* d1[5]; int st1[5]; size_t badd[5];
#pragma unroll
    for (int k = 0; k < 5; ++k) {
        const int sg = w * 5 + k;
        if (sg < 4) {
            const int p  = sg * 64 + lane;
            const int rw = p >> 2;
            const int ch = (p & 3) ^ ((p >> 4) & 3);
            g1[k] = Ab + (size_t)(m0 + rw) * 512 + ch * 16;
            d1[k] = AL + sg * 1024; st1[k] = 4096; badd[k] = 0;
        } else {
            const int p  = (sg - 4) * 64 + lane;
            const int r  = p >> 2;
            const int bR = ((r >> 6) << 6) + 4 * (r & 15) + ((r >> 4) & 3);
            const int ch = (p & 3) ^ ((p >> 3) & 3);
            g1[k] = W1b + (size_t)bR * 512 + ch * 16;
            d1[k] = BL + (sg - 4) * 1024; st1[k] = 16384; badd[k] = 131072;  // 256 rows * 512B
        }
    }
    // phase-2 B segs: w2 rows 0-255 (rb=2048B), k-offset per chunk = hc*512B
    const char* g2[4]; char* d2[4];
#pragma unroll
    for (int k = 0; k < 4; ++k) {
        const int p  = (w * 4 + k) * 64 + lane;
        const int r  = p >> 2;
        const int bR = ((r >> 6) << 6) + 4 * (r & 15) + ((r >> 4) & 3);
        const int ch = (p & 3) ^ ((p >> 3) & 3);
        g2[k] = W2b + (size_t)bR * 2048 + ch * 16;
        d2[k] = BL + (w * 4 + k) * 1024;
    }

    const int mrow = lane & 15;
    const int q    = lane >> 4;
    const int kA   = ((q ^ (mrow >> 2)) & 3) * 16;
    const int kB   = ((q ^ (mrow >> 1)) & 3) * 16;
    const int coll = mrow;
    const int rowh = q * 4;
    // h-write addressing: k_in_chunk = wc + 4*coll + ni
    const int hk    = w * 2 + (coll >> 3);      // kstep 0..7
    const int hslot = (coll >> 1) & 3;          // 16B chunk within 64B row
    const int hhalf = (coll & 1) * 8;           // 8B half within chunk

    f32x4 acc2[4][4];
#pragma unroll
    for (int i = 0; i < 4; ++i)
#pragma unroll
        for (int j = 0; j < 4; ++j) acc2[i][j] = (f32x4){0.f, 0.f, 0.f, 0.f};

#define STG1(BUF, T, HC)                                                        \
    do {                                                                        \
        const size_t kb_ = (size_t)(T) * 64;                                    \
        _Pragma("unroll")                                                       \
        for (int k = 0; k < 5; ++k)                                             \
            gl_lds16(g1[k] + kb_ + (size_t)(HC) * badd[k], d1[k] + (BUF) * st1[k]); \
    } while (0)

#define STG2(BUF, T, HC)                                                        \
    do {                                                                        \
        const size_t kb_ = (size_t)(HC) * 512 + (size_t)(T) * 64;               \
        _Pragma("unroll")                                                       \
        for (int k = 0; k < 4; ++k)                                             \
            gl_lds16(g2[k] + kb_, d2[k] + (BUF) * 16384);                       \
    } while (0)

#pragma unroll 1
    for (int hc = 0; hc < 4; ++hc) {
        // ---- phase 1: h = gelu(A @ w1_chunk^T + b1_chunk), into Hlds ----
        f32x4 acc1[4][4];
#pragma unroll
        for (int i = 0; i < 4; ++i)
#pragma unroll
            for (int j = 0; j < 4; ++j) acc1[i][j] = (f32x4){0.f, 0.f, 0.f, 0.f};

        STG1(0, 0, hc);
        STG1(1, 1, hc);
#pragma unroll 1
        for (int i = 0; i < 8; ++i) {
            const int cur = i & 1;
            if (i < 7) asm volatile("s_waitcnt vmcnt(5)" ::: "memory");
            else       asm volatile("s_waitcnt vmcnt(0)" ::: "memory");
            __builtin_amdgcn_s_barrier();
            bf16x8 af[4], bfr[4];
#pragma unroll
            for (int ii = 0; ii < 4; ++ii)
                af[ii] = *(const bf16x8*)(AL + cur * 4096 + (ii * 16 + mrow) * 64 + kA);
#pragma unroll
            for (int ii = 0; ii < 4; ++ii)
                bfr[ii] = *(const bf16x8*)(BL + cur * 16384 + (wc + ii * 16 + mrow) * 64 + kB);
#pragma unroll
            for (int mi = 0; mi < 4; ++mi)
#pragma unroll
                for (int ni = 0; ni < 4; ++ni)
                    acc1[mi][ni] = __builtin_amdgcn_mfma_f32_16x16x32_bf16(af[mi], bfr[ni], acc1[mi][ni], 0, 0, 0);
            __builtin_amdgcn_s_barrier();
            if (i < 6) STG1(cur, i + 2, hc);
        }

        // h-write: gelu+bias, bf16, into Hlds A-operand layout
        {
            const int col0h = wc + 4 * coll;                    // k index within chunk
            const float4 bv1 = *(const float4*)(b1 + hc * 256 + col0h);
#pragma unroll
            for (int mi = 0; mi < 4; ++mi) {
#pragma unroll
                for (int j = 0; j < 4; ++j) {
                    const int row = mi * 16 + rowh + j;         // 0..63 local
                    bf16x4 hb = {(__bf16)gelu_fast(acc1[mi][0][j] + bv1.x),
                                 (__bf16)gelu_fast(acc1[mi][1][j] + bv1.y),
                                 (__bf16)gelu_fast(acc1[mi][2][j] + bv1.z),
                                 (__bf16)gelu_fast(acc1[mi][3][j] + bv1.w)};
                    *(bf16x4*)(HL + hk * 4096 + row * 64
                               + ((hslot ^ ((row >> 2) & 3)) * 16) + hhalf) = hb;
                }
            }
        }
        __syncthreads();   // h fully written before any wave reads it

        // ---- phase 2: acc2 += h @ w2_chunk^T (B-only staging) ----
        STG2(0, 0, hc);
        STG2(1, 1, hc);
#pragma unroll 1
        for (int i = 0; i < 8; ++i) {
            const int cur = i & 1;
            if (i < 7) asm volatile("s_waitcnt vmcnt(4)" ::: "memory");
            else       asm volatile("s_waitcnt vmcnt(0)" ::: "memory");
            __builtin_amdgcn_s_barrier();
            bf16x8 af[4], bfr[4];
#pragma unroll
            for (int ii = 0; ii < 4; ++ii)
                af[ii] = *(const bf16x8*)(HL + i * 4096 + (ii * 16 + mrow) * 64 + kA);
#pragma unroll
            for (int ii = 0; ii < 4; ++ii)
                bfr[ii] = *(const bf16x8*)(BL + cur * 16384 + (wc + ii * 16 + mrow) * 64 + kB);
#pragma unroll
            for (int mi = 0; mi < 4; ++mi)
#pragma unroll
                for (int ni = 0; ni < 4; ++ni)
                    acc2[mi][ni] = __builtin_amdgcn_mfma_f32_16x16x32_bf16(af[mi], bfr[ni], acc2[mi][ni], 0, 0, 0);
            __builtin_amdgcn_s_barrier();
            if (i < 6) STG2(cur, i + 2, hc);
        }
        __syncthreads();   // Hlds free for next chunk's phase-1 writes
    }
#undef STG1
#undef STG2

    // epilogue: out = acc2 + b2 + yb (f32)
    const int col0 = wc + 4 * coll;
    const float4 bv = *(const float4*)(b2 + col0);
#pragma unroll
    for (int mi = 0; mi < 4; ++mi) {
#pragma unroll
        for (int j = 0; j < 4; ++j) {
            const int row = m0 + mi * 16 + rowh + j;
            const size_t idx = (size_t)row * 256 + col0;
            const bf16x4 r = *(const bf16x4*)(yb + idx);
            float4 v = make_float4(acc2[mi][0][j] + bv.x + (float)r[0],
                                   acc2[mi][1][j] + bv.y + (float)r[1],
                                   acc2[mi][2][j] + bv.z + (float)r[2],
                                   acc2[mi][3][j] + bv.w + (float)r[3]);
            *(float4*)(out + idx) = v;
        }
    }
}

// ---------------- DCNv3 core: block = 8 tokens; thread = token x 8 channels ----------------
// xp is fp16 -> gather loop is pure v_pk_fma_f16. Phase C indexed (p, tg) so consecutive
// lanes write consecutive 8B slots. NO launch_bounds 2nd arg (r10/r11 spill lesson).
__global__ __launch_bounds__(256)
void dcn_kernel(const _Float16* __restrict__ xp, const __bf16* __restrict__ om,
                __bf16* __restrict__ out) {
    __shared__ __align__(16) __bf16 rawb[TPB][NOFFM];   // off[0,288)+mask[288,432) bf16
    __shared__ ushort4 sidx[NPTS][TPB * NGRP];          // 4 clamped tap indices (y*W+x)
    __shared__ f16x4   swt[NPTS][TPB * NGRP];           // 4 bilinear wts * softmax(mask), fp16
    const int tid = threadIdx.x;
    // XCD-chunked bijective swizzle: 3136 blocks = 8 XCDs x 392; XCD k -> image k
    const int bid = blockIdx.x;
    const int b   = (bid & 7) * 392 + (bid >> 3);
    const int t0  = b * TPB;

    for (int e = tid; e < (TPB * NOFFM) / 8; e += 256)
        *(bf16x8*)(&rawb[0][0] + e * 8) = *(const bf16x8*)(om + (size_t)t0 * NOFFM + e * 8);
    __syncthreads();

    if (tid < TPB * NGRP) {
        const int lt = tid >> 4, g = tid & 15;
        __bf16* m = &rawb[lt][288 + g * 9];
        float e[9];
        float mx = -1e30f;
#pragma unroll
        for (int p = 0; p < 9; ++p) { e[p] = (float)m[p]; mx = fmaxf(mx, e[p]); }
        float s = 0.f;
#pragma unroll
        for (int p = 0; p < 9; ++p) { e[p] = __expf(e[p] - mx); s += e[p]; }
        const float inv = 1.f / s;
#pragma unroll
        for (int p = 0; p < 9; ++p) m[p] = (__bf16)(e[p] * inv);
    }
    __syncthreads();

    for (int e = tid; e < NPTS * TPB * NGRP; e += 256) {
        const int p  = e >> 7;          // 128 = TPB*NGRP
        const int tg = e & 127;
        const int lt = tg >> 4, g = tg & 15;
        const int t  = t0 + lt;
        const int hw = t % HW_;
        const int h = hw / WW, w0 = hw % WW;
        const float offx = (float)rawb[lt][g * 18 + p * 2 + 0];
        const float offy = (float)rawb[lt][g * 18 + p * 2 + 1];
        const float pm   = (float)rawb[lt][288 + g * 9 + p];
        const int kx = p / 3, ky = p % 3;          // w-major point order
        const float fx = (float)(w0 + kx - 1) + offx;
        const float fy = (float)(h  + ky - 1) + offy;
        const float x0f = floorf(fx), y0f = floorf(fy);
        const float wx = fx - x0f, wy = fy - y0f;
        const int x0 = (int)x0f, y0 = (int)y0f;
        const bool xv0 = (unsigned)x0 < WW, xv1 = (unsigned)(x0 + 1) < WW;
        const bool yv0 = (unsigned)y0 < HH, yv1 = (unsigned)(y0 + 1) < HH;
        const int xc0 = min(max(x0, 0), WW - 1), xc1 = min(max(x0 + 1, 0), WW - 1);
        const int yc0 = min(max(y0, 0), HH - 1), yc1 = min(max(y0 + 1, 0), HH - 1);
        sidx[p][tg] = make_ushort4((unsigned short)(yc0 * WW + xc0),
                                   (unsigned short)(yc0 * WW + xc1),
                                   (unsigned short)(yc1 * WW + xc0),
                                   (unsigned short)(yc1 * WW + xc1));
        f16x4 wv;
        wv[0] = (_Float16)((xv0 && yv0) ? (1.f - wx) * (1.f - wy) * pm : 0.f);
        wv[1] = (_Float16)((xv1 && yv0) ? wx * (1.f - wy) * pm : 0.f);
        wv[2] = (_Float16)((xv0 && yv1) ? (1.f - wx) * wy * pm : 0.f);
        wv[3] = (_Float16)((xv1 && yv1) ? wx * wy * pm : 0.f);
        swt[p][tg] = wv;
    }
    __syncthreads();

    const int lt = tid >> 5, lane = tid & 31;
    const int g = lane >> 1;
    const int t = t0 + lt;
    const int n = t / HW_;
    const int tg = lt * 16 + g;
    const _Float16* base = xp + (size_t)n * HW_ * CCH + lane * 8;
    f16x8 acc = {(_Float16)0, (_Float16)0, (_Float16)0, (_Float16)0,
                 (_Float16)0, (_Float16)0, (_Float16)0, (_Float16)0};
#pragma unroll
    for (int p = 0; p < NPTS; ++p) {
        const ushort4 id = sidx[p][tg];
        const f16x4   wh = swt[p][tg];
        f16x8 v0 = *(const f16x8*)(base + (size_t)id.x * CCH);
        f16x8 v1 = *(const f16x8*)(base + (size_t)id.y * CCH);
        f16x8 v2 = *(const f16x8*)(base + (size_t)id.z * CCH);
        f16x8 v3 = *(const f16x8*)(base + (size_t)id.w * CCH);
        acc += v0 * splat8(wh[0]) + v1 * splat8(wh[1])
             + v2 * splat8(wh[2]) + v3 * splat8(wh[3]);
    }
    bf16x8 ob;
#pragma unroll
    for (int k = 0; k < 8; ++k) ob[k] = (__bf16)(float)acc[k];
    *(bf16x8*)(out + (size_t)t * CCH + lane * 8) = ob;
}

// ---------------- launch ----------------
extern "C" void kernel_launch(void* const* d_in, const int* in_sizes, int n_in,
                              void* d_out, int out_size, void* d_ws, size_t ws_size,
                              hipStream_t stream) {
    const float* x      = (const float*)d_in[0];
    const float* ln1_g  = (const float*)d_in[1];
    const float* ln1_b  = (const float*)d_in[2];
    const float* dw_w   = (const float*)d_in[3];
    const float* dw_b   = (const float*)d_in[4];
    const float* off_w  = (const float*)d_in[5];
    const float* off_b  = (const float*)d_in[6];
    const float* mask_w = (const float*)d_in[7];
    const float* mask_b = (const float*)d_in[8];
    const float* inp_w  = (const float*)d_in[9];
    const float* inp_b  = (const float*)d_in[10];
    const float* out_w  = (const float*)d_in[11];
    const float* out_b  = (const float*)d_in[12];
    const float* ln2_g  = (const float*)d_in[13];
    const float* ln2_b  = (const float*)d_in[14];
    const float* fc1_w  = (const float*)d_in[15];
    const float* fc1_b  = (const float*)d_in[16];
    const float* fc2_w  = (const float*)d_in[17];
    const float* fc2_b  = (const float*)d_in[18];
    float* out = (float*)d_out;

    char* ws = (char*)d_ws;
    size_t o = 0;
    auto alloc = [&](size_t bytes) { size_t r = o; o += (bytes + 255) & ~(size_t)255; return r; };
    __bf16* yb    = (__bf16*)(ws + alloc((size_t)NTOK * CCH * 2));    // y residual, bf16
    __bf16* x1b   = (__bf16*)(ws + alloc((size_t)NTOK * CCH * 2));    // reused as l2b
    __bf16* lnb   = (__bf16*)(ws + alloc((size_t)NTOK * CCH * 2));    // reused as dcnb
    __bf16* xpb   = (__bf16*)(ws + alloc((size_t)NTOK * CCH * 2));    // fp16 input-proj (2B elems)
    __bf16* offmb = (__bf16*)(ws + alloc((size_t)NTOK * NOFFM * 2));  // bf16 merged off+mask
    __bf16* wib   = (__bf16*)(ws + alloc((size_t)65536 * 2));
    __bf16* wob   = (__bf16*)(ws + alloc((size_t)65536 * 2));
    __bf16* wcat  = (__bf16*)(ws + alloc((size_t)110592 * 2));        // off(288)+mask(144) x 256
    __bf16* w1b   = (__bf16*)(ws + alloc((size_t)262144 * 2));
    __bf16* w2b   = (__bf16*)(ws + alloc((size_t)262144 * 2));
    float*  bcat  = (float*)(ws + alloc((size_t)432 * 4));
    if (ws_size < o) return;

    __bf16* dcnb = lnb;                 // dead after out-proj
    __bf16* l2b  = x1b;                 // live into mlp

    // weights cvt + bias concat + LN1, one dispatch
    cvtln_kernel<<<750 + NTOK / 4, 256, 0, stream>>>(
        inp_w, out_w, off_w, mask_w, fc1_w, fc2_w, off_b, mask_b,
        wib, wob, wcat, w1b, w2b, bcat, x, ln1_g, ln1_b, lnb);

    dwconv_kernel<<<NTOK / 4, 256, 0, stream>>>(lnb, dw_w, dw_b, x1b);
    // offm (x1b @ wcat, N=432 in 512 span, NB=2, bf16) + inp (lnb @ wib, N=256, NB=1, fp16)
    gemm_dual_kernel<<<392 * 2 + 392, 256, 0, stream>>>(
        x1b, wcat, bcat, offmb, NOFFM, 2, 392 * 2,
        lnb, wib, inp_b, xpb, 256, 1);
    // deformable sampling (XCD-chunked swizzle inside; fp16 taps)
    dcn_kernel<<<NTOK / TPB, 256, 0, stream>>>((const _Float16*)xpb, offmb, dcnb);
    // output projection + residual(x f32) -> y bf16
    gemm_kernel<4><<<392, 256, 0, stream>>>(dcnb, wob, out_b, x, nullptr, yb, 256, 256, 1);
    // LN2 (bf16 in) -> bf16
    ln_b_kernel<<<NTOK / 4, 256, 0, stream>>>(yb, ln2_g, ln2_b, l2b);
    // fused MLP: fc1 + GELU + fc2 + residual(y) -> out f32 (h1 stays in LDS)
    mlp_kernel<<<392, 256, 0, stream>>>(l2b, w1b, w2b, fc1_b, fc2_b, yb, out);
}

// Round 16
// 157.323 us; speedup vs baseline: 1.2208x; 1.2208x over previous
//
#include <hip/hip_runtime.h>
#include <hip/hip_bf16.h>
#include <math.h>

// Problem constants
#define NTOK 25088      // 8*56*56
#define HW_  3136
#define HH   56
#define WW   56
#define CCH  256
#define NGRP 16
#define NPTS 9
#define HIDN 1024
#define NOFFM 432       // merged off(288)+mask(144) row width
#define TPB  8          // tokens per dcn block (thread = token x 8 channels)

typedef __attribute__((ext_vector_type(8))) __bf16 bf16x8;
typedef __attribute__((ext_vector_type(4))) __bf16 bf16x4;
typedef __attribute__((ext_vector_type(4))) float  f32x4;
typedef __attribute__((ext_vector_type(4))) _Float16 f16x4;
typedef __attribute__((ext_vector_type(8))) _Float16 f16x8;

static __device__ __forceinline__ void gl_lds16(const void* g, void* l) {
    __builtin_amdgcn_global_load_lds((const __attribute__((address_space(1))) void*)g,
                                     (__attribute__((address_space(3))) void*)l, 16, 0, 0);
}

static __device__ __forceinline__ f16x8 splat8(_Float16 w) {
    f16x8 r = {w, w, w, w, w, w, w, w};
    return r;
}

// tanh-form GELU via identity 0.5v(1+tanh z) = v * sigmoid(2z); fast rcp.
static __device__ __forceinline__ float gelu_fast(float v) {
    float v2 = v * v;
    float z2 = fmaf(0.0713548163f * v, v2, 1.5957691216f * v);   // 2z
    float r  = __builtin_amdgcn_rcpf(__expf(-z2) + 1.0f);        // sigmoid(2z)
    return v * r;
}

// ---------------- weight cvt + bias concat + LN1, fused (independent block ranges) ----------------
__global__ __launch_bounds__(256)
void cvtln_kernel(const float* __restrict__ inp_w, const float* __restrict__ out_w,
                  const float* __restrict__ off_w, const float* __restrict__ mask_w,
                  const float* __restrict__ fc1_w, const float* __restrict__ fc2_w,
                  const float* __restrict__ off_b, const float* __restrict__ mask_b,
                  __bf16* wib, __bf16* wob, __bf16* wcat, __bf16* w1b, __bf16* w2b,
                  float* bcat,
                  const float* __restrict__ x, const float* __restrict__ ln1_g,
                  const float* __restrict__ ln1_b, __bf16* __restrict__ lnb) {
    if (blockIdx.x < 750) {
        int i = blockIdx.x * 256 + threadIdx.x;
        if (i >= 191488) {
            int j = i - 191488;
            if (j < 432) bcat[j] = (j < 288) ? off_b[j] : mask_b[j - 288];
            return;
        }
        const float* s; __bf16* d; int off;
        if (i < 16384)       { s = inp_w;  d = wib;          off = i; }
        else if (i < 32768)  { s = out_w;  d = wob;          off = i - 16384; }
        else if (i < 51200)  { s = off_w;  d = wcat;         off = i - 32768; }
        else if (i < 60416)  { s = mask_w; d = wcat + 73728; off = i - 51200; }
        else if (i < 125952) { s = fc1_w;  d = w1b;          off = i - 60416; }
        else                 { s = fc2_w;  d = w2b;          off = i - 125952; }
        float4 v = ((const float4*)s)[off];
        bf16x4 o = {(__bf16)v.x, (__bf16)v.y, (__bf16)v.z, (__bf16)v.w};
        ((bf16x4*)d)[off] = o;
        return;
    }
    // LN1: one wave per token, f32 in, bf16 out
    int gid  = (blockIdx.x - 750) * 256 + threadIdx.x;
    int t    = gid >> 6;
    int lane = threadIdx.x & 63;
    if (t >= NTOK) return;
    float4 v = ((const float4*)(x + (size_t)t * CCH))[lane];
    float s = v.x + v.y + v.z + v.w;
#pragma unroll
    for (int o = 1; o < 64; o <<= 1) s += __shfl_xor(s, o);
    float mu = s * 0.00390625f;
    float dx = v.x - mu, dy = v.y - mu, dz = v.z - mu, dw = v.w - mu;
    float q = dx * dx + dy * dy + dz * dz + dw * dw;
#pragma unroll
    for (int o = 1; o < 64; o <<= 1) q += __shfl_xor(q, o);
    float rstd = rsqrtf(q * 0.00390625f + 1e-6f);
    float4 gg = ((const float4*)ln1_g)[lane];
    float4 bb = ((const float4*)ln1_b)[lane];
    bf16x4 ob = {(__bf16)(dx * rstd * gg.x + bb.x), (__bf16)(dy * rstd * gg.y + bb.y),
                 (__bf16)(dz * rstd * gg.z + bb.z), (__bf16)(dw * rstd * gg.w + bb.w)};
    ((bf16x4*)(lnb + (size_t)t * CCH))[lane] = ob;
}

// ---------------- depthwise 3x3 conv (pad 1), bf16 in, thread = token x 4 channels ----------------
__global__ __launch_bounds__(256)
void dwconv_kernel(const __bf16* __restrict__ ln, const float* __restrict__ wt,
                   const float* __restrict__ bias, __bf16* __restrict__ out) {
    int gid = blockIdx.x * 256 + threadIdx.x;
    int t = gid >> 6;
    int cq = gid & 63;
    if (t >= NTOK) return;
    int n = t / HW_, hw = t % HW_;
    int h = hw / WW, w0 = hw % WW;
    float4 a = ((const float4*)bias)[cq];
    const bf16x4* l4 = (const bf16x4*)ln;
    const float4* w4 = (const float4*)wt;
#pragma unroll
    for (int ky = 0; ky < 3; ++ky) {
        int y = h + ky - 1;
        if (y < 0 || y >= HH) continue;
#pragma unroll
        for (int kx = 0; kx < 3; ++kx) {
            int x = w0 + kx - 1;
            if (x < 0 || x >= WW) continue;
            bf16x4 v = l4[(size_t)(n * HW_ + y * WW + x) * 64 + cq];
            float4 ww = w4[(ky * 3 + kx) * 64 + cq];
            a.x += (float)v[0] * ww.x; a.y += (float)v[1] * ww.y;
            a.z += (float)v[2] * ww.z; a.w += (float)v[3] * ww.w;
        }
    }
    bf16x4 ob = {(__bf16)a.x, (__bf16)a.y, (__bf16)a.z, (__bf16)a.w};
    ((bf16x4*)out)[(size_t)t * 64 + cq] = ob;
}

// ---------------- GEMM body: out[M,N] = A[M,K] @ W[N,K]^T + bias ----------------
// BM=64 x BN=256, 256 threads = 4 waves, wave tile 64x64 (acc 4x4). Depth-2 prefetch,
// COUNTED vmcnt(5). A: linear LDS rows, slot XOR s=(row>>2)&3. B: row-permuted LDS
// (row r holds W-row n0+64*(r>>6)+4*(r&15)+((r>>4)&3)), slot XOR s=(r>>1)&3 ->
// lane owns 4 consecutive output cols. NO launch_bounds 2nd arg (r10/r11 spills).
// EPI 2: bf16 = gelu(gemm+bias) ; EPI 3: bf16 = gemm+bias ;
// EPI 5: f32 = gemm+bias+resid_bf16 ; EPI 6: fp16 = gemm+bias ;
// EPI 7: y = gemm+bias+resid_f32 -> yb bf16 (outb), AND l2b = LN(y) bf16 (outb2)
//        (fused out-proj + LN2; per-row reduce via 16-lane shfl groups + LDS, Ndim=256)
template <int EPI>
static __device__ __forceinline__ void gemm_body(
        const __bf16* __restrict__ A, const __bf16* __restrict__ W,
        const float* __restrict__ bias, const float* __restrict__ residf,
        const __bf16* __restrict__ residb, float* __restrict__ outf,
        __bf16* __restrict__ outb, const int Ndim, const int Kdim,
        const int NB, const int lin,
        const float* __restrict__ lng, const float* __restrict__ lnbt,
        __bf16* __restrict__ outb2) {
    __shared__ __align__(16) __bf16 Alds[2][64 * 32];    // 8 KB
    __shared__ __align__(16) __bf16 Blds[2][256 * 32];   // 32 KB

    const int tid  = threadIdx.x;
    const int w    = tid >> 6;
    const int lane = tid & 63;
    const int m0 = (lin / NB) * 64;
    const int n0 = (lin % NB) * 256;
    const int wc = w * 64;

    f32x4 acc[4][4];
#pragma unroll
    for (int i = 0; i < 4; ++i)
#pragma unroll
        for (int j = 0; j < 4; ++j) acc[i][j] = (f32x4){0.f, 0.f, 0.f, 0.f};

    const char* Ab = (const char*)A;
    const char* Wb = (const char*)W;
    char* AL = (char*)&Alds[0][0];
    char* BL = (char*)&Blds[0][0];
    const size_t rb = (size_t)Kdim * 2;

    const char* gsrc[5];
    char*       ldst[5];
    int         lstep[5];
#pragma unroll
    for (int k = 0; k < 5; ++k) {
        const int sg = w * 5 + k;
        if (sg < 4) {          // A segment
            const int p  = sg * 64 + lane;
            const int rw = p >> 2;
            const int ch = (p & 3) ^ ((p >> 4) & 3);
            gsrc[k]  = Ab + (size_t)(m0 + rw) * rb + ch * 16;
            ldst[k]  = AL + sg * 1024;
            lstep[k] = 4096;
        } else {               // B segment
            const int p  = (sg - 4) * 64 + lane;
            const int r  = p >> 2;
            int bR = n0 + ((r >> 6) << 6) + 4 * (r & 15) + ((r >> 4) & 3);
            if (bR > Ndim - 1) bR = Ndim - 1;
            const int ch = (p & 3) ^ ((p >> 3) & 3);
            gsrc[k]  = Wb + (size_t)bR * rb + ch * 16;
            ldst[k]  = BL + (sg - 4) * 1024;
            lstep[k] = 16384;
        }
    }

#define STAGE(BUF, TILE)                                              \
    do {                                                              \
        const size_t kb_ = (size_t)(TILE) * 64;                       \
        _Pragma("unroll")                                             \
        for (int k = 0; k < 5; ++k)                                   \
            gl_lds16(gsrc[k] + kb_, ldst[k] + (BUF) * lstep[k]);      \
    } while (0)

    const int mrow = lane & 15;
    const int q    = lane >> 4;
    const int kA   = ((q ^ (mrow >> 2)) & 3) * 16;
    const int kB   = ((q ^ (mrow >> 1)) & 3) * 16;

    const int nt = Kdim >> 5;
    STAGE(0, 0);
    if (nt > 1) STAGE(1, 1);
    for (int i = 0; i < nt; ++i) {
        const int cur = i & 1;
        if (i + 1 < nt) asm volatile("s_waitcnt vmcnt(5)" ::: "memory");
        else            asm volatile("s_waitcnt vmcnt(0)" ::: "memory");
        __builtin_amdgcn_s_barrier();     // tile i resident in buf[cur] for all waves
        bf16x8 af[4], bfr[4];
#pragma unroll
        for (int ii = 0; ii < 4; ++ii)
            af[ii] = *(const bf16x8*)(AL + cur * 4096 + (ii * 16 + mrow) * 64 + kA);
#pragma unroll
        for (int ii = 0; ii < 4; ++ii)
            bfr[ii] = *(const bf16x8*)(BL + cur * 16384 + (wc + ii * 16 + mrow) * 64 + kB);
#pragma unroll
        for (int mi = 0; mi < 4; ++mi)
#pragma unroll
            for (int ni = 0; ni < 4; ++ni)
                acc[mi][ni] = __builtin_amdgcn_mfma_f32_16x16x32_bf16(af[mi], bfr[ni], acc[mi][ni], 0, 0, 0);
        __builtin_amdgcn_s_barrier();     // all waves consumed buf[cur]; safe to overwrite
        if (i + 2 < nt) STAGE(cur, i + 2);
    }
#undef STAGE

    const int coll = lane & 15;
    const int rowh = q * 4;
    const int col0 = n0 + wc + 4 * coll;

    if (EPI == 7) {
        // fused out-proj + LN2: Ndim==256, n0==0, block owns 64 full rows.
        const float4 bv = *(const float4*)(bias + col0);
        // y = acc + bias + x ; write yb
#pragma unroll
        for (int mi = 0; mi < 4; ++mi) {
#pragma unroll
            for (int j = 0; j < 4; ++j) {
                const int row = m0 + mi * 16 + rowh + j;
                const size_t idx = (size_t)row * 256 + col0;
                const float4 r = *(const float4*)(residf + idx);
                acc[mi][0][j] += bv.x + r.x;
                acc[mi][1][j] += bv.y + r.y;
                acc[mi][2][j] += bv.z + r.z;
                acc[mi][3][j] += bv.w + r.w;
                bf16x4 ob = {(__bf16)acc[mi][0][j], (__bf16)acc[mi][1][j],
                             (__bf16)acc[mi][2][j], (__bf16)acc[mi][3][j]};
                *(bf16x4*)(outb + idx) = ob;
            }
        }
        // per-row partial sums: reduce over the 16-lane coll-group, stash per-wave in LDS
        // (Alds is dead after the final K-loop barrier -> reuse as float2[4][64])
        float2* lnp = (float2*)AL;
#pragma unroll
        for (int mi = 0; mi < 4; ++mi) {
#pragma unroll
            for (int j = 0; j < 4; ++j) {
                float s  = acc[mi][0][j] + acc[mi][1][j] + acc[mi][2][j] + acc[mi][3][j];
                float q2 = acc[mi][0][j] * acc[mi][0][j] + acc[mi][1][j] * acc[mi][1][j]
                         + acc[mi][2][j] * acc[mi][2][j] + acc[mi][3][j] * acc[mi][3][j];
#pragma unroll
                for (int o = 1; o < 16; o <<= 1) {
                    s  += __shfl_xor(s, o);
                    q2 += __shfl_xor(q2, o);
                }
                if (coll == 0) lnp[w * 64 + mi * 16 + rowh + j] = make_float2(s, q2);
            }
        }
        __syncthreads();
        const float4 gg = *(const float4*)(lng + col0);
        const float4 bb = *(const float4*)(lnbt + col0);
#pragma unroll
        for (int mi = 0; mi < 4; ++mi) {
#pragma unroll
            for (int j = 0; j < 4; ++j) {
                const int rl = mi * 16 + rowh + j;
                float s = 0.f, q2 = 0.f;
#pragma unroll
                for (int ww = 0; ww < 4; ++ww) {
                    const float2 p = lnp[ww * 64 + rl];
                    s += p.x; q2 += p.y;
                }
                const float mu   = s * 0.00390625f;
                const float var  = q2 * 0.00390625f - mu * mu;
                const float rstd = rsqrtf(var + 1e-6f);
                const size_t idx = (size_t)(m0 + rl) * 256 + col0;
                bf16x4 ob = {(__bf16)((acc[mi][0][j] - mu) * rstd * gg.x + bb.x),
                             (__bf16)((acc[mi][1][j] - mu) * rstd * gg.y + bb.y),
                             (__bf16)((acc[mi][2][j] - mu) * rstd * gg.z + bb.z),
                             (__bf16)((acc[mi][3][j] - mu) * rstd * gg.w + bb.w)};
                *(bf16x4*)(outb2 + idx) = ob;
            }
        }
    } else if (col0 < Ndim) {
        const float4 bv = *(const float4*)(bias + col0);
#pragma unroll
        for (int mi = 0; mi < 4; ++mi) {
#pragma unroll
            for (int j = 0; j < 4; ++j) {
                const int row = m0 + mi * 16 + rowh + j;
                const size_t idx = (size_t)row * (size_t)Ndim + col0;
                float4 v = make_float4(acc[mi][0][j] + bv.x, acc[mi][1][j] + bv.y,
                                       acc[mi][2][j] + bv.z, acc[mi][3][j] + bv.w);
                if (EPI == 2) {
                    bf16x4 ob = {(__bf16)gelu_fast(v.x), (__bf16)gelu_fast(v.y),
                                 (__bf16)gelu_fast(v.z), (__bf16)gelu_fast(v.w)};
                    *(bf16x4*)(outb + idx) = ob;
                } else if (EPI == 3) {
                    bf16x4 ob = {(__bf16)v.x, (__bf16)v.y, (__bf16)v.z, (__bf16)v.w};
                    *(bf16x4*)(outb + idx) = ob;
                } else if (EPI == 5) {
                    const bf16x4 r = *(const bf16x4*)(residb + idx);
                    v.x += (float)r[0]; v.y += (float)r[1];
                    v.z += (float)r[2]; v.w += (float)r[3];
                    *(float4*)(outf + idx) = v;
                } else {   // EPI 6: fp16 out
                    f16x4 ob = {(_Float16)v.x, (_Float16)v.y, (_Float16)v.z, (_Float16)v.w};
                    *(f16x4*)((_Float16*)outb + idx) = ob;
                }
            }
        }
    }
}

template <int EPI>
__global__ __launch_bounds__(256)
void gemm_kernel(const __bf16* __restrict__ A, const __bf16* __restrict__ W,
                 const float* __restrict__ bias, const float* __restrict__ residf,
                 const __bf16* __restrict__ residb, float* __restrict__ outf,
                 __bf16* __restrict__ outb, const int Ndim, const int Kdim, const int NB) {
    // XCD-chunked bijective remap (gridDim.x % 8 == 0); n-fastest within chunk
    const int chunk = gridDim.x >> 3;
    const int lin   = (blockIdx.x & 7) * chunk + (blockIdx.x >> 3);
    gemm_body<EPI>(A, W, bias, residf, residb, outf, outb, Ndim, Kdim, NB, lin,
                   nullptr, nullptr, nullptr);
}

// fused out-proj + LN2: yb = dcnb@wob^T + out_b + x ; l2b = LN(y)
__global__ __launch_bounds__(256)
void gemm_ln_kernel(const __bf16* __restrict__ A, const __bf16* __restrict__ W,
                    const float* __restrict__ bias, const float* __restrict__ residf,
                    __bf16* __restrict__ yb, __bf16* __restrict__ l2b,
                    const float* __restrict__ lng, const float* __restrict__ lnbt) {
    const int chunk = gridDim.x >> 3;
    const int lin   = (blockIdx.x & 7) * chunk + (blockIdx.x >> 3);
    gemm_body<7>(A, W, bias, residf, nullptr, nullptr, yb, 256, 256, 1, lin,
                 lng, lnbt, l2b);
}

// two independent projections in one dispatch: offm (bf16 out) + inp (fp16 out)
__global__ __launch_bounds__(256)
void gemm_dual_kernel(const __bf16* __restrict__ A1, const __bf16* __restrict__ W1,
                      const float* __restrict__ b1, __bf16* __restrict__ o1,
                      const int N1, const int NB1, const int split,
                      const __bf16* __restrict__ A2, const __bf16* __restrict__ W2,
                      const float* __restrict__ b2, __bf16* __restrict__ o2,
                      const int N2, const int NB2) {
    const int chunk = gridDim.x >> 3;
    const int lin   = (blockIdx.x & 7) * chunk + (blockIdx.x >> 3);
    if (lin < split)
        gemm_body<3>(A1, W1, b1, nullptr, nullptr, nullptr, o1, N1, 256, NB1, lin,
                     nullptr, nullptr, nullptr);
    else
        gemm_body<6>(A2, W2, b2, nullptr, nullptr, nullptr, o2, N2, 256, NB2, lin - split,
                     nullptr, nullptr, nullptr);
}

// ---------------- DCNv3 core: block = 8 tokens; thread = token x 8 channels ----------------
// xp is fp16 -> gather loop is pure v_pk_fma_f16. Phase C indexed (p, tg) so consecutive
// lanes write consecutive 8B slots. NO launch_bounds 2nd arg (r10/r11 spill lesson).
__global__ __launch_bounds__(256)
void dcn_kernel(const _Float16* __restrict__ xp, const __bf16* __restrict__ om,
                __bf16* __restrict__ out) {
    __shared__ __align__(16) __bf16 rawb[TPB][NOFFM];   // off[0,288)+mask[288,432) bf16
    __shared__ ushort4 sidx[NPTS][TPB * NGRP];          // 4 clamped tap indices (y*W+x)
    __shared__ f16x4   swt[NPTS][TPB * NGRP];           // 4 bilinear wts * softmax(mask), fp16
    const int tid = threadIdx.x;
    // XCD-chunked bijective swizzle: 3136 blocks = 8 XCDs x 392; XCD k -> image k
    const int bid = blockIdx.x;
    const int b   = (bid & 7) * 392 + (bid >> 3);
    const int t0  = b * TPB;

    for (int e = tid; e < (TPB * NOFFM) / 8; e += 256)
        *(bf16x8*)(&rawb[0][0] + e * 8) = *(const bf16x8*)(om + (size_t)t0 * NOFFM + e * 8);
    __syncthreads();

    if (tid < TPB * NGRP) {
        const int lt = tid >> 4, g = tid & 15;
        __bf16* m = &rawb[lt][288 + g * 9];
        float e[9];
        float mx = -1e30f;
#pragma unroll
        for (int p = 0; p < 9; ++p) { e[p] = (float)m[p]; mx = fmaxf(mx, e[p]); }
        float s = 0.f;
#pragma unroll
        for (int p = 0; p < 9; ++p) { e[p] = __expf(e[p] - mx); s += e[p]; }
        const float inv = 1.f / s;
#pragma unroll
        for (int p = 0; p < 9; ++p) m[p] = (__bf16)(e[p] * inv);
    }
    __syncthreads();

    for (int e = tid; e < NPTS * TPB * NGRP; e += 256) {
        const int p  = e >> 7;          // 128 = TPB*NGRP
        const int tg = e & 127;
        const int lt = tg >> 4, g = tg & 15;
        const int t  = t0 + lt;
        const int hw = t % HW_;
        const int h = hw / WW, w0 = hw % WW;
        const float offx = (float)rawb[lt][g * 18 + p * 2 + 0];
        const float offy = (float)rawb[lt][g * 18 + p * 2 + 1];
        const float pm   = (float)rawb[lt][288 + g * 9 + p];
        const int kx = p / 3, ky = p % 3;          // w-major point order
        const float fx = (float)(w0 + kx - 1) + offx;
        const float fy = (float)(h  + ky - 1) + offy;
        const float x0f = floorf(fx), y0f = floorf(fy);
        const float wx = fx - x0f, wy = fy - y0f;
        const int x0 = (int)x0f, y0 = (int)y0f;
        const bool xv0 = (unsigned)x0 < WW, xv1 = (unsigned)(x0 + 1) < WW;
        const bool yv0 = (unsigned)y0 < HH, yv1 = (unsigned)(y0 + 1) < HH;
        const int xc0 = min(max(x0, 0), WW - 1), xc1 = min(max(x0 + 1, 0), WW - 1);
        const int yc0 = min(max(y0, 0), HH - 1), yc1 = min(max(y0 + 1, 0), HH - 1);
        sidx[p][tg] = make_ushort4((unsigned short)(yc0 * WW + xc0),
                                   (unsigned short)(yc0 * WW + xc1),
                                   (unsigned short)(yc1 * WW + xc0),
                                   (unsigned short)(yc1 * WW + xc1));
        f16x4 wv;
        wv[0] = (_Float16)((xv0 && yv0) ? (1.f - wx) * (1.f - wy) * pm : 0.f);
        wv[1] = (_Float16)((xv1 && yv0) ? wx * (1.f - wy) * pm : 0.f);
        wv[2] = (_Float16)((xv0 && yv1) ? (1.f - wx) * wy * pm : 0.f);
        wv[3] = (_Float16)((xv1 && yv1) ? wx * wy * pm : 0.f);
        swt[p][tg] = wv;
    }
    __syncthreads();

    const int lt = tid >> 5, lane = tid & 31;
    const int g = lane >> 1;
    const int t = t0 + lt;
    const int n = t / HW_;
    const int tg = lt * 16 + g;
    const _Float16* base = xp + (size_t)n * HW_ * CCH + lane * 8;
    f16x8 acc = {(_Float16)0, (_Float16)0, (_Float16)0, (_Float16)0,
                 (_Float16)0, (_Float16)0, (_Float16)0, (_Float16)0};
#pragma unroll
    for (int p = 0; p < NPTS; ++p) {
        const ushort4 id = sidx[p][tg];
        const f16x4   wh = swt[p][tg];
        f16x8 v0 = *(const f16x8*)(base + (size_t)id.x * CCH);
        f16x8 v1 = *(const f16x8*)(base + (size_t)id.y * CCH);
        f16x8 v2 = *(const f16x8*)(base + (size_t)id.z * CCH);
        f16x8 v3 = *(const f16x8*)(base + (size_t)id.w * CCH);
        acc += v0 * splat8(wh[0]) + v1 * splat8(wh[1])
             + v2 * splat8(wh[2]) + v3 * splat8(wh[3]);
    }
    bf16x8 ob;
#pragma unroll
    for (int k = 0; k < 8; ++k) ob[k] = (__bf16)(float)acc[k];
    *(bf16x8*)(out + (size_t)t * CCH + lane * 8) = ob;
}

// ---------------- launch ----------------
extern "C" void kernel_launch(void* const* d_in, const int* in_sizes, int n_in,
                              void* d_out, int out_size, void* d_ws, size_t ws_size,
                              hipStream_t stream) {
    const float* x      = (const float*)d_in[0];
    const float* ln1_g  = (const float*)d_in[1];
    const float* ln1_b  = (const float*)d_in[2];
    const float* dw_w   = (const float*)d_in[3];
    const float* dw_b   = (const float*)d_in[4];
    const float* off_w  = (const float*)d_in[5];
    const float* off_b  = (const float*)d_in[6];
    const float* mask_w = (const float*)d_in[7];
    const float* mask_b = (const float*)d_in[8];
    const float* inp_w  = (const float*)d_in[9];
    const float* inp_b  = (const float*)d_in[10];
    const float* out_w  = (const float*)d_in[11];
    const float* out_b  = (const float*)d_in[12];
    const float* ln2_g  = (const float*)d_in[13];
    const float* ln2_b  = (const float*)d_in[14];
    const float* fc1_w  = (const float*)d_in[15];
    const float* fc1_b  = (const float*)d_in[16];
    const float* fc2_w  = (const float*)d_in[17];
    const float* fc2_b  = (const float*)d_in[18];
    float* out = (float*)d_out;

    char* ws = (char*)d_ws;
    size_t o = 0;
    auto alloc = [&](size_t bytes) { size_t r = o; o += (bytes + 255) & ~(size_t)255; return r; };
    __bf16* yb    = (__bf16*)(ws + alloc((size_t)NTOK * CCH * 2));    // y residual, bf16
    __bf16* x1b   = (__bf16*)(ws + alloc((size_t)NTOK * CCH * 2));    // reused as l2b
    __bf16* lnb   = (__bf16*)(ws + alloc((size_t)NTOK * CCH * 2));    // reused as dcnb; h1b starts here
    __bf16* xpb   = (__bf16*)(ws + alloc((size_t)NTOK * CCH * 2));    // fp16 input-proj (2B elems)
    __bf16* offmb = (__bf16*)(ws + alloc((size_t)NTOK * NOFFM * 2));  // bf16 merged off+mask
    alloc(6 * 1024 * 1024);                                           // pad so h1 (51.4MB) fits at lnb
    __bf16* wib   = (__bf16*)(ws + alloc((size_t)65536 * 2));
    __bf16* wob   = (__bf16*)(ws + alloc((size_t)65536 * 2));
    __bf16* wcat  = (__bf16*)(ws + alloc((size_t)110592 * 2));        // off(288)+mask(144) x 256
    __bf16* w1b   = (__bf16*)(ws + alloc((size_t)262144 * 2));
    __bf16* w2b   = (__bf16*)(ws + alloc((size_t)262144 * 2));
    float*  bcat  = (float*)(ws + alloc((size_t)432 * 4));
    if (ws_size < o) return;

    __bf16* dcnb = lnb;                 // dead after out-proj
    __bf16* l2b  = x1b;                 // live into fc1
    __bf16* h1b  = lnb;                 // 51.4MB over lnb+xpb+offmb+pad (all dead by fc1)

    // weights cvt + bias concat + LN1, one dispatch
    cvtln_kernel<<<750 + NTOK / 4, 256, 0, stream>>>(
        inp_w, out_w, off_w, mask_w, fc1_w, fc2_w, off_b, mask_b,
        wib, wob, wcat, w1b, w2b, bcat, x, ln1_g, ln1_b, lnb);

    dwconv_kernel<<<NTOK / 4, 256, 0, stream>>>(lnb, dw_w, dw_b, x1b);
    // offm (x1b @ wcat, N=432 in 512 span, NB=2, bf16) + inp (lnb @ wib, N=256, NB=1, fp16)
    gemm_dual_kernel<<<392 * 2 + 392, 256, 0, stream>>>(
        x1b, wcat, bcat, offmb, NOFFM, 2, 392 * 2,
        lnb, wib, inp_b, xpb, 256, 1);
    // deformable sampling (XCD-chunked swizzle inside; fp16 taps)
    dcn_kernel<<<NTOK / TPB, 256, 0, stream>>>((const _Float16*)xpb, offmb, dcnb);
    // fused: output projection + residual(x f32) -> yb bf16 AND LN2(y f32) -> l2b bf16
    gemm_ln_kernel<<<392, 256, 0, stream>>>(dcnb, wob, out_b, x, yb, l2b, ln2_g, ln2_b);
    // fc1 + GELU -> bf16
    gemm_kernel<2><<<392 * 4, 256, 0, stream>>>(l2b, w1b, fc1_b, nullptr, nullptr, nullptr, h1b, 1024, 256, 4);
    // fc2 + residual(y bf16) -> out f32
    gemm_kernel<5><<<392, 256, 0, stream>>>(h1b, w2b, fc2_b, nullptr, yb, out, nullptr, 256, 1024, 1);
}